// Round 6
// baseline (123.734 us; speedup 1.0000x reference)
//
#include <hip/hip_runtime.h>

// SelfAttentionPool, fused kernel v10 (round 11).
// History: v4 28.6 kernel -> v5/v6 compute shaving (null) -> v7 reg dbuf
// (spill, 43.5) -> v8 LDS prefetch (~2us) -> v9 deferred stores (null).
// Kernel pinned ~29us vs ~18us BW floor; insensitive to everything except
// added traffic => remaining suspect = the 14 s_barriers/block (phase
// exposure), not instruction counts.
// v10: barriers 14 -> 6. After each graph's scatter (B4), ALL remaining work
//      is wave-local and redundant: every wave assembles all 100 z from the
//      finalized zp/dis/a, ranks via broadcast LDS reads of its private zs
//      row, forms newid from its own ballots (deterministic f64 => all waves
//      agree), and stores its share using ds_bpermute register lookups.
//      B5/B6a/B6/B7 deleted for both graphs. Stores issue per-wave right
//      after topk and drain under the next graph's phases. x loads issued
//      before edge loads (dot is the critical path); B-edge loads moved to
//      the prefetch point. zp: 4 wave-pair slices, double-buffered by graph
//      parity (cross-wave init/read hazard). LDS 79.2KB -> 2 blocks/CU.
// Numerics: z pipeline stays f64; zp regrouping changes rounding ~1e-16 only.
//
// Output (float32): x_new (80000*128) | edge0 (E) | edge1 (E) | batch_new (80000)

#define NPG   100
#define EPG   1600
#define KNUM  80
#define FDIM  128
#define BT    512
#define NF4   (NPG * FDIM / 4)   // 3200 float4 of x per graph
#define NE4   (EPG / 4)          // 400 int4 per edge row
#define NCH   (NF4 / BT)         // 6 full chunks
#define NREM  (NF4 - NCH * BT)   // 128 remainder float4
#define P4    5                  // padded stride, 4 partials/node

struct Smem {
    alignas(16) float xB[NPG * FDIM];   // 51200B staged x for graph B
    int4   edge4[NE4];                  //  6400B packed: s | (d<<16)
    int    cnt[8][NPG];                 //  3200B per-wave degree
    double part[NPG * P4];              //  4000B dot partials (4/node)
    double zs[8][NPG];                  //  6400B per-wave private z copies
    double dis[NPG];                    //   800B
    double a[NPG];                      //   800B s * dis
    double zp[2][4][NPG];               //  6400B [parity][wavepair][node]
};                                      // 79200B -> 2 blocks/CU

typedef __attribute__((address_space(1))) const unsigned int gu32;
typedef __attribute__((address_space(3))) unsigned int lu32;

// Barrier WITHOUT vmcnt drain (LDS ordering only; prefetch/stores stay live).
__device__ __forceinline__ void bar_nodrain() {
    asm volatile("s_waitcnt lgkmcnt(0)" ::: "memory");
    __builtin_amdgcn_s_barrier();
    asm volatile("" ::: "memory");
}

// All-lane-active register lookup across the wave (exec-masked source lanes
// return 0 from ds_bpermute -> callers keep all 64 lanes active here).
__device__ __forceinline__ int bperm_i(int idx, int lo, int hi) {
    int l = __builtin_amdgcn_ds_bpermute((idx & 63) << 2, lo);
    int h = __builtin_amdgcn_ds_bpermute((idx & 63) << 2, hi);
    return idx < 64 ? l : h;
}
__device__ __forceinline__ float bperm_f(int idx, float lo, float hi) {
    int l = __builtin_amdgcn_ds_bpermute((idx & 63) << 2, __float_as_int(lo));
    int h = __builtin_amdgcn_ds_bpermute((idx & 63) << 2, __float_as_int(hi));
    return __int_as_float(idx < 64 ? l : h);
}

template<bool FROMLDS, bool PF>
__device__ __forceinline__
void process_graph(Smem& sm, int g, int gp, int tid, int wave, int lane,
                   float4 th, float4 (&v)[NCH], float4& vR, int4 es, int4 ed,
                   const float4* pfsrc, const int* ei, int4& esB, int4& edB,
                   float* __restrict__ out, int E_total, int out_x_elems)
{
    const int  base = g * NPG;
    const bool hasE = tid < NE4;
    const bool hasR = tid < NREM;
    int* sh_edge = (int*)sm.edge4;
    const float4* xl = (const float4*)sm.xB;

    // per-wave private init (same-wave DS ordering, no barrier)
    {
        int*    cw = sm.cnt[wave];
        double* zw = sm.zp[gp][wave >> 1];
        for (int i = lane; i < NPG; i += 64) cw[i] = 0;
        for (int i = lane; i < NPG; i += 64) zw[i] = 0.0;   // both pair-waves
    }

    // ---- dot first (x is the critical path): 3 shfl folds -> 4 part/node
    #pragma unroll
    for (int i = 0; i < NCH; ++i) {
        int idx = i * BT + tid;
        if (FROMLDS) v[i] = xl[idx];
        double dp = (double)v[i].x * th.x + (double)v[i].y * th.y
                  + (double)v[i].z * th.z + (double)v[i].w * th.w;
        dp += __shfl_xor(dp, 1, 64);
        dp += __shfl_xor(dp, 2, 64);
        dp += __shfl_xor(dp, 4, 64);
        if ((lane & 7) == 0)
            sm.part[(idx >> 5) * P4 + ((lane & 31) >> 3)] = dp;
    }
    if (hasR) {
        int idx = NCH * BT + tid;
        if (FROMLDS) vR = xl[idx];
        double dp = (double)vR.x * th.x + (double)vR.y * th.y
                  + (double)vR.z * th.z + (double)vR.w * th.w;
        dp += __shfl_xor(dp, 1, 64);
        dp += __shfl_xor(dp, 2, 64);
        dp += __shfl_xor(dp, 4, 64);
        if ((lane & 7) == 0)
            sm.part[(idx >> 5) * P4 + ((lane & 31) >> 3)] = dp;
    }

    // ---- edge pack + per-wave degree histogram
    int4 p = {0, 0, 0, 0};
    if (hasE) {
        int4 s4 = es, d4 = ed;
        s4.x -= base; s4.y -= base; s4.z -= base; s4.w -= base;
        d4.x -= base; d4.y -= base; d4.z -= base; d4.w -= base;
        p.x = s4.x | (d4.x << 16); p.y = s4.y | (d4.y << 16);
        p.z = s4.z | (d4.z << 16); p.w = s4.w | (d4.w << 16);
        sm.edge4[tid] = p;
        int* cw = sm.cnt[wave];
        atomicAdd(&cw[s4.x], 1); atomicAdd(&cw[s4.y], 1);
        atomicAdd(&cw[s4.z], 1); atomicAdd(&cw[s4.w], 1);
    }

    if (PF) {   // async-stage next graph's x (zero VGPR) + next edges (regs)
        #pragma unroll
        for (int i = 0; i < NCH; ++i) {
            int idx = i * BT + tid;
            __builtin_amdgcn_global_load_lds((gu32*)(pfsrc + idx),
                (lu32*)(sm.xB + (size_t)(i * BT + wave * 64) * 4), 16, 0, 0);
        }
        if (wave < 2) {
            int idx = NCH * BT + tid;
            __builtin_amdgcn_global_load_lds((gu32*)(pfsrc + idx),
                (lu32*)(sm.xB + (size_t)(NCH * BT + wave * 64) * 4), 16, 0, 0);
        }
        if (hasE) {
            esB = ((const int4*)(ei + (size_t)(g + 1) * EPG))[tid];
            edB = ((const int4*)(ei + (size_t)E_total + (size_t)(g + 1) * EPG))[tid];
        }
    }
    bar_nodrain();                                // B2: part, edges, cnt

    // ---- reduce: 1 thread/node: 4 partials + deg -> dis, a
    if (tid < NPG) {
        const double* pr = sm.part + tid * P4;
        double s = (pr[0] + pr[1]) + (pr[2] + pr[3]);
        int deg = 1 + sm.cnt[0][tid] + sm.cnt[1][tid] + sm.cnt[2][tid]
                    + sm.cnt[3][tid] + sm.cnt[4][tid] + sm.cnt[5][tid]
                    + sm.cnt[6][tid] + sm.cnt[7][tid];
        double dis = 1.0 / sqrt((double)deg);
        sm.dis[tid] = dis;
        sm.a[tid]   = s * dis;
    }
    bar_nodrain();                                // B3: dis/a ready

    // ---- z scatter into wave-pair slices
    {
        double* zw = sm.zp[gp][wave >> 1];
        for (int j = tid; j < EPG; j += BT) {
            int e = sh_edge[j];
            atomicAdd(&zw[e >> 16], sm.a[e & 0xffff]);
        }
    }
    bar_nodrain();                                // B4: scatter done
    // ======== everything below is wave-local (no more barriers) ========

    // ---- z assembly: lane owns nodes lane and 64+lane (<36)
    const double* zq0 = sm.zp[gp][0];
    const double* zq1 = sm.zp[gp][1];
    const double* zq2 = sm.zp[gp][2];
    const double* zq3 = sm.zp[gp][3];
    double zlo = (sm.a[lane] + zq0[lane] + zq1[lane] + zq2[lane] + zq3[lane])
               * sm.dis[lane];
    const bool hiv = lane < (NPG - 64);
    const int  nh  = 64 + lane;
    double zhi = -1.0e300;
    if (hiv)
        zhi = (sm.a[nh] + zq0[nh] + zq1[nh] + zq2[nh] + zq3[nh]) * sm.dis[nh];
    double* zw = sm.zs[wave];
    zw[lane] = zlo;
    if (hiv) zw[nh] = zhi;

    // ---- rank via broadcast reads of the wave-private z row
    int rlo = 0, rhi = 0;
    #pragma unroll 4
    for (int j = 0; j < NPG; ++j) {
        double zj = zw[j];
        rlo += (int)((zj > zlo) | ((zj == zlo) & (j < lane)));
        rhi += (int)((zj > zhi) | ((zj == zhi) & (j < nh)));
    }
    const bool klo = rlo < KNUM;
    const bool khi = hiv && (rhi < KNUM);
    unsigned long long mlo = __ballot(klo);
    unsigned long long mhi = __ballot(khi);
    unsigned long long below = (1ull << lane) - 1ull;
    int nlo = klo ? g * KNUM + __popcll(mlo & below) : -1;
    int nhi = khi ? g * KNUM + __popcll(mlo) + __popcll(mhi & below) : -1;
    float slo = 1.0f / (1.0f + __expf(-(float)zlo));
    float shi = 1.0f / (1.0f + __expf(-(float)zhi));   // 0 if invalid

    if (PF)   // xB prefetch landed? (our big stores not issued yet -> cheap)
        asm volatile("s_waitcnt vmcnt(0)" ::: "memory");

    if (wave == 0) {      // batch_new (one wave, values identical across waves)
        float* bn = out + (size_t)out_x_elems + 2 * (size_t)E_total;
        if (klo) bn[nlo] = (float)g;
        if (khi) bn[nhi] = (float)g;
    }

    // ---- x_new stores (lookups all-lane-active; store predicated)
    float4* outx = (float4*)out;
    #pragma unroll
    for (int i = 0; i < NCH; ++i) {
        int idx = i * BT + tid;
        int row = idx >> 5;
        int nid = bperm_i(row, nlo, nhi);
        float sc = bperm_f(row, slo, shi);
        if (nid >= 0) {
            float4 w4 = FROMLDS ? xl[idx] : v[i];
            float4 o;
            o.x = w4.x * sc; o.y = w4.y * sc;
            o.z = w4.z * sc; o.w = w4.w * sc;
            outx[(size_t)nid * 32 + (idx & 31)] = o;
        }
    }
    if (hasR) {           // waves 0,1 fully active (wave-uniform)
        int idx = NCH * BT + tid;
        int row = idx >> 5;
        int nid = bperm_i(row, nlo, nhi);
        float sc = bperm_f(row, slo, shi);
        if (nid >= 0) {
            float4 w4 = FROMLDS ? xl[idx] : vR;
            float4 o;
            o.x = w4.x * sc; o.y = w4.y * sc;
            o.z = w4.z * sc; o.w = w4.w * sc;
            outx[(size_t)nid * 32 + (idx & 31)] = o;
        }
    }

    // ---- edge relabel (lookups all-lane-active; p=0 for non-hasE lanes)
    {
        float4 o0, o1;
        {
            int na = bperm_i(p.x & 0xffff, nlo, nhi);
            int nb = bperm_i(p.x >> 16,    nlo, nhi);
            bool vv = (na >= 0) && (nb >= 0);
            o0.x = vv ? (float)na : -1.0f; o1.x = vv ? (float)nb : -1.0f;
        }
        {
            int na = bperm_i(p.y & 0xffff, nlo, nhi);
            int nb = bperm_i(p.y >> 16,    nlo, nhi);
            bool vv = (na >= 0) && (nb >= 0);
            o0.y = vv ? (float)na : -1.0f; o1.y = vv ? (float)nb : -1.0f;
        }
        {
            int na = bperm_i(p.z & 0xffff, nlo, nhi);
            int nb = bperm_i(p.z >> 16,    nlo, nhi);
            bool vv = (na >= 0) && (nb >= 0);
            o0.z = vv ? (float)na : -1.0f; o1.z = vv ? (float)nb : -1.0f;
        }
        {
            int na = bperm_i(p.w & 0xffff, nlo, nhi);
            int nb = bperm_i(p.w >> 16,    nlo, nhi);
            bool vv = (na >= 0) && (nb >= 0);
            o0.w = vv ? (float)na : -1.0f; o1.w = vv ? (float)nb : -1.0f;
        }
        if (hasE) {
            float* e0 = out + out_x_elems;
            float* e1 = e0 + E_total;
            ((float4*)e0)[(size_t)g * NE4 + tid] = o0;
            ((float4*)e1)[(size_t)g * NE4 + tid] = o1;
        }
    }
}

__global__ __launch_bounds__(BT, 4)
void sagpool_fused10(const float* __restrict__ x,
                     const int*   __restrict__ ei,
                     const float* __restrict__ theta,
                     float* __restrict__ out,
                     int E_total, int out_x_elems, int n_graphs)
{
    __shared__ Smem sm;
    const int tid  = threadIdx.x;
    const int wave = tid >> 6;
    const int lane = tid & 63;
    const int gA   = blockIdx.x * 2;
    const int gB   = gA + 1;
    const bool hasE = tid < NE4;
    const bool hasR = tid < NREM;
    const bool doB  = gB < n_graphs;

    const float4 th = ((const float4*)theta)[lane & 31];

    // x loads FIRST (dot is the critical path), then A edges.
    float4 v[NCH];
    float4 vR = {0.f, 0.f, 0.f, 0.f};
    const float4* xA = (const float4*)(x + (size_t)gA * NPG * FDIM);
    #pragma unroll
    for (int i = 0; i < NCH; ++i) v[i] = xA[i * BT + tid];
    if (hasR) vR = xA[NCH * BT + tid];

    int4 esA = {0,0,0,0}, edA = {0,0,0,0}, esB = {0,0,0,0}, edB = {0,0,0,0};
    if (hasE) {
        esA = ((const int4*)(ei + (size_t)gA * EPG))[tid];
        edA = ((const int4*)(ei + (size_t)E_total + (size_t)gA * EPG))[tid];
    }

    const float4* xB = (const float4*)(x + (size_t)gB * NPG * FDIM);
    process_graph<false, true>(sm, gA, 0, tid, wave, lane, th, v, vR,
                               esA, edA, xB, ei, esB, edB,
                               out, E_total, out_x_elems);
    if (doB)
        process_graph<true, false>(sm, gB, 1, tid, wave, lane, th, v, vR,
                                   esB, edB, nullptr, ei, esB, edB,
                                   out, E_total, out_x_elems);
}

extern "C" void kernel_launch(void* const* d_in, const int* in_sizes, int n_in,
                              void* d_out, int out_size, void* d_ws, size_t ws_size,
                              hipStream_t stream)
{
    const float* x     = (const float*)d_in[0];
    const int*   ei    = (const int*)d_in[1];
    const float* theta = (const float*)d_in[3];
    float* out = (float*)d_out;

    const int N = in_sizes[0] / FDIM;        // 100000
    const int E = in_sizes[1] / 2;           // 1600000
    const int B = N / NPG;                   // 1000
    const int out_x_elems = B * KNUM * FDIM; // 10,240,000
    const int nb = (B + 1) / 2;              // 500 blocks

    sagpool_fused10<<<dim3(nb), dim3(BT), 0, stream>>>(x, ei, theta, out,
                                                       E, out_x_elems, B);
}

// Round 7
// 109.491 us; speedup vs baseline: 1.1301x; 1.1301x over previous
//
#include <hip/hip_runtime.h>

// SelfAttentionPool, fused kernel v11 (round 12).
// History: v4 28.6 (1g/block, 3 blk/CU) -> v5/v6 compute shave (null) ->
// v7 reg dbuf (spill, 43.5) -> v8 LDS prefetch (26.5, best) -> v9 deferred
// stores (null) -> v10 wave-redundant tail (44.2: +8us redundant VALU/LDS;
// counters CLEAN: WRITE 52.8MB exact, all pipes <32% busy -> LATENCY-bound,
// occupancy capped at 50% by 2 blk/CU).
// v11: occupancy play. 1 graph/block, distributed (non-redundant) tail,
//      Smem trimmed to ~20KB (zp 8->4 wave-pair slices, 4 partials/node via
//      3 shfl folds, no prefetch buffer), __launch_bounds__(512,8) caps
//      VGPR at 64 (v10 measured 52 with same reg tile). 1000 blocks =
//      250 CU x 4 blk/CU = 32 waves/CU (100%): four independent blocks per
//      CU hide each other's barrier/latency stalls.
// Numerics: z pipeline stays f64; zp 4-slice regrouping ~1e-16 reordering.
//
// Output (float32): x_new (80000*128) | edge0 (E) | edge1 (E) | batch_new (80000)

#define NPG   100
#define EPG   1600
#define KNUM  80
#define FDIM  128
#define BT    512
#define NF4   (NPG * FDIM / 4)   // 3200 float4 of x per graph
#define NE4   (EPG / 4)          // 400 int4 per edge row
#define NCH   (NF4 / BT)         // 6 full chunks
#define NREM  (NF4 - NCH * BT)   // 128 remainder float4
#define P4    5                  // padded stride, 4 partials/node

struct Smem {
    int4   edge4[NE4];                  //  6400B packed: s | (d<<16)
    int    cnt[8][NPG];                 //  3200B per-wave degree (same-wave
                                        //        init->atomic ordering)
    double part[NPG * P4];              //  4000B dot partials (4/node)
    double dis[NPG];                    //   800B
    double a[NPG];                      //   800B s * dis
    double zp[4][NPG];                  //  3200B wave-pair scatter slices
    double z[NPG];                      //   800B
    unsigned long long mask7[8];        //    64B
    int    newid[NPG];                  //   400B
    float  scalen[NPG];                 //   400B
};                                      // ~20.1KB -> LDS allows 7; waves cap 4

__global__ __launch_bounds__(BT, 8)
void sagpool_fused11(const float* __restrict__ x,
                     const int*   __restrict__ ei,
                     const float* __restrict__ theta,
                     float* __restrict__ out,
                     int E_total, int out_x_elems)
{
    __shared__ Smem sm;
    const int g    = blockIdx.x;
    const int tid  = threadIdx.x;
    const int wave = tid >> 6;
    const int lane = tid & 63;
    const int base = g * NPG;
    const bool hasE = tid < NE4;
    const bool hasR = tid < NREM;
    int* sh_edge = (int*)sm.edge4;

    const float4 th = ((const float4*)theta)[lane & 31];

    // ---- x loads FIRST (dot is the critical path), then edges
    float4 v[NCH];
    float4 vR = {0.f, 0.f, 0.f, 0.f};
    const float4* xb4 = (const float4*)(x + (size_t)base * FDIM);
    #pragma unroll
    for (int i = 0; i < NCH; ++i) v[i] = xb4[i * BT + tid];
    if (hasR) vR = xb4[NCH * BT + tid];

    int4 es = {0,0,0,0}, ed = {0,0,0,0};
    if (hasE) {
        es = ((const int4*)(ei + (size_t)g * EPG))[tid];
        ed = ((const int4*)(ei + (size_t)E_total + (size_t)g * EPG))[tid];
    }

    // ---- init: cnt per-wave (same-wave ordering); zp pair slices (both
    // waves write 0 idempotently; ordered vs scatter by B2+B3)
    {
        int* cw = sm.cnt[wave];
        for (int i = lane; i < NPG; i += 64) cw[i] = 0;
        double* zw = sm.zp[wave >> 1];
        for (int i = lane; i < NPG; i += 64) zw[i] = 0.0;
    }

    // ---- dot: f64 partial, 3 shfl folds (8 lanes -> 1), 4 partials/node
    #pragma unroll
    for (int i = 0; i < NCH; ++i) {
        int idx = i * BT + tid;
        double dp = (double)v[i].x * th.x + (double)v[i].y * th.y
                  + (double)v[i].z * th.z + (double)v[i].w * th.w;
        dp += __shfl_xor(dp, 1, 64);
        dp += __shfl_xor(dp, 2, 64);
        dp += __shfl_xor(dp, 4, 64);
        if ((lane & 7) == 0)
            sm.part[(idx >> 5) * P4 + ((lane & 31) >> 3)] = dp;
    }
    if (hasR) {
        int idx = NCH * BT + tid;
        double dp = (double)vR.x * th.x + (double)vR.y * th.y
                  + (double)vR.z * th.z + (double)vR.w * th.w;
        dp += __shfl_xor(dp, 1, 64);
        dp += __shfl_xor(dp, 2, 64);
        dp += __shfl_xor(dp, 4, 64);
        if ((lane & 7) == 0)
            sm.part[(idx >> 5) * P4 + ((lane & 31) >> 3)] = dp;
    }

    // ---- edge pack + per-wave degree histogram
    int4 p = {0,0,0,0};
    if (hasE) {
        int4 s4 = es, d4 = ed;
        s4.x -= base; s4.y -= base; s4.z -= base; s4.w -= base;
        d4.x -= base; d4.y -= base; d4.z -= base; d4.w -= base;
        p.x = s4.x | (d4.x << 16); p.y = s4.y | (d4.y << 16);
        p.z = s4.z | (d4.z << 16); p.w = s4.w | (d4.w << 16);
        sm.edge4[tid] = p;
        int* cw = sm.cnt[wave];
        atomicAdd(&cw[s4.x], 1); atomicAdd(&cw[s4.y], 1);
        atomicAdd(&cw[s4.z], 1); atomicAdd(&cw[s4.w], 1);
    }
    __syncthreads();                              // B2: part, edges, cnt

    // ---- reduce: 1 thread/node: 4 partials + deg -> dis, a
    if (tid < NPG) {
        const double* pr = sm.part + tid * P4;
        double s = (pr[0] + pr[1]) + (pr[2] + pr[3]);
        int deg = 1 + sm.cnt[0][tid] + sm.cnt[1][tid] + sm.cnt[2][tid]
                    + sm.cnt[3][tid] + sm.cnt[4][tid] + sm.cnt[5][tid]
                    + sm.cnt[6][tid] + sm.cnt[7][tid];
        double dis = 1.0 / sqrt((double)deg);
        sm.dis[tid] = dis;
        sm.a[tid]   = s * dis;
    }
    __syncthreads();                              // B3: dis/a ready

    // ---- z scatter into wave-pair slices (dis[d] hoisted out)
    {
        double* zw = sm.zp[wave >> 1];
        for (int j = tid; j < EPG; j += BT) {
            int e = sh_edge[j];
            atomicAdd(&zw[e >> 16], sm.a[e & 0xffff]);
        }
    }
    __syncthreads();                              // B4: scatter done

    if (tid < NPG) {
        double zi = sm.a[tid]                     // self-loop term
                  + (sm.zp[0][tid] + sm.zp[1][tid])
                  + (sm.zp[2][tid] + sm.zp[3][tid]);
        sm.z[tid] = zi * sm.dis[tid];
        sm.newid[tid] = -1;
    }
    __syncthreads();                              // B5: z ready

    // ---- top-k rank, 4 threads/node (25 scans each) + shfl combine
    const bool rk = tid < 4 * NPG;
    const int  n2 = tid >> 2;
    int r = 0;
    double zn = 0.0;
    if (rk) {
        zn = sm.z[n2];
        const int j0 = (tid & 3) * 25;
        #pragma unroll 5
        for (int j = j0; j < j0 + 25; ++j) {
            double zj = sm.z[j];
            r += (int)((zj > zn) | ((zj == zn) & (j < n2)));
        }
    }
    r += __shfl_xor(r, 1, 64);
    r += __shfl_xor(r, 2, 64);                    // all 4 lanes hold full rank
    const bool lead = rk && ((tid & 3) == 0) && (r < KNUM);
    unsigned long long m = __ballot(lead);        // leader bits at lanes 4k
    if (lane == 0) sm.mask7[wave] = m;
    __syncthreads();                              // B6a: masks ready

    if (lead) {
        int before = __popcll(m & ((1ull << lane) - 1ull));
        for (int w2 = 0; w2 < wave; ++w2) before += __popcll(sm.mask7[w2]);
        int row = g * KNUM + before;
        sm.newid[n2]  = row;
        sm.scalen[n2] = 1.0f / (1.0f + __expf(-(float)zn));
        out[(size_t)out_x_elems + 2 * (size_t)E_total + row] = (float)g;
    }
    __syncthreads();                              // B6: newid/scalen ready

    // ---- x_new straight from the register-resident tile
    float4* outx = (float4*)out;
    #pragma unroll
    for (int i = 0; i < NCH; ++i) {
        int idx = i * BT + tid;
        int row = idx >> 5;
        int nid = sm.newid[row];
        if (nid >= 0) {
            float sc = sm.scalen[row];
            float4 o;
            o.x = v[i].x * sc; o.y = v[i].y * sc;
            o.z = v[i].z * sc; o.w = v[i].w * sc;
            outx[(size_t)nid * 32 + (idx & 31)] = o;
        }
    }
    if (hasR) {
        int idx = NCH * BT + tid;
        int row = idx >> 5;
        int nid = sm.newid[row];
        if (nid >= 0) {
            float sc = sm.scalen[row];
            float4 o;
            o.x = vR.x * sc; o.y = vR.y * sc;
            o.z = vR.z * sc; o.w = vR.w * sc;
            outx[(size_t)nid * 32 + (idx & 31)] = o;
        }
    }

    // ---- edge relabel from register-resident packed edges
    if (hasE) {
        float* e0 = out + out_x_elems;
        float* e1 = e0 + E_total;
        float4 o0, o1;
        {
            int a_ = sm.newid[p.x & 0xffff], b_ = sm.newid[p.x >> 16];
            bool vv = (a_ >= 0) && (b_ >= 0);
            o0.x = vv ? (float)a_ : -1.0f; o1.x = vv ? (float)b_ : -1.0f;
        }
        {
            int a_ = sm.newid[p.y & 0xffff], b_ = sm.newid[p.y >> 16];
            bool vv = (a_ >= 0) && (b_ >= 0);
            o0.y = vv ? (float)a_ : -1.0f; o1.y = vv ? (float)b_ : -1.0f;
        }
        {
            int a_ = sm.newid[p.z & 0xffff], b_ = sm.newid[p.z >> 16];
            bool vv = (a_ >= 0) && (b_ >= 0);
            o0.z = vv ? (float)a_ : -1.0f; o1.z = vv ? (float)b_ : -1.0f;
        }
        {
            int a_ = sm.newid[p.w & 0xffff], b_ = sm.newid[p.w >> 16];
            bool vv = (a_ >= 0) && (b_ >= 0);
            o0.w = vv ? (float)a_ : -1.0f; o1.w = vv ? (float)b_ : -1.0f;
        }
        ((float4*)e0)[(size_t)g * NE4 + tid] = o0;
        ((float4*)e1)[(size_t)g * NE4 + tid] = o1;
    }
}

extern "C" void kernel_launch(void* const* d_in, const int* in_sizes, int n_in,
                              void* d_out, int out_size, void* d_ws, size_t ws_size,
                              hipStream_t stream)
{
    const float* x     = (const float*)d_in[0];
    const int*   ei    = (const int*)d_in[1];
    const float* theta = (const float*)d_in[3];
    float* out = (float*)d_out;

    const int N = in_sizes[0] / FDIM;        // 100000
    const int E = in_sizes[1] / 2;           // 1600000
    const int B = N / NPG;                   // 1000
    const int out_x_elems = B * KNUM * FDIM; // 10,240,000

    sagpool_fused11<<<dim3(B), dim3(BT), 0, stream>>>(x, ei, theta, out,
                                                      E, out_x_elems);
}

// Round 8
// 108.944 us; speedup vs baseline: 1.1358x; 1.0050x over previous
//
#include <hip/hip_runtime.h>

// SelfAttentionPool, fused kernel v12 (round 13).
// History: v4 28.6 -> v5/v6 compute shave (null) -> v7 reg dbuf (spill 43.5)
// -> v8 GPB=2 LDS prefetch (26.5) -> v9 deferred stores (null) -> v10
// wave-redundant tail (44.2, latency-bound evidence) -> v11 max occupancy
// (26, best total 109.5).
// Convergence evidence: three independent structures (v8 pipeline, v9 store
// scheduling, v11 occupancy) all land at ~26us vs ~18.7us pure-BW floor.
// GPB=2 and 4-blk/CU occupancy are mutually exclusive (500 blocks -> 2/CU),
// and both plateau identically => bound is the memory system serving ~118MB
// mixed R/W at ~71% effective + load ramp + store drain, not instructions.
// v12: v11 + last free lever: all barriers -> bar_nodrain (no vmcnt(0)
//      drain; only B6a/B6 had pending stores: the batch_new leader dwords),
//      and store order x_new -> edges -> batch_new so the big coalesced
//      stream issues first. Pure micro-refinement of the best structure.
// Numerics: unchanged f64 z pipeline.
//
// Output (float32): x_new (80000*128) | edge0 (E) | edge1 (E) | batch_new (80000)

#define NPG   100
#define EPG   1600
#define KNUM  80
#define FDIM  128
#define BT    512
#define NF4   (NPG * FDIM / 4)   // 3200 float4 of x per graph
#define NE4   (EPG / 4)          // 400 int4 per edge row
#define NCH   (NF4 / BT)         // 6 full chunks
#define NREM  (NF4 - NCH * BT)   // 128 remainder float4
#define P4    5                  // padded stride, 4 partials/node

struct Smem {
    int4   edge4[NE4];                  //  6400B packed: s | (d<<16)
    int    cnt[8][NPG];                 //  3200B per-wave degree
    double part[NPG * P4];              //  4000B dot partials (4/node)
    double dis[NPG];                    //   800B
    double a[NPG];                      //   800B s * dis
    double zp[4][NPG];                  //  3200B wave-pair scatter slices
    double z[NPG];                      //   800B
    unsigned long long mask7[8];        //    64B
    int    newid[NPG];                  //   400B
    float  scalen[NPG];                 //   400B
};                                      // ~20.1KB; waves cap at 4 blk/CU

// Barrier WITHOUT vmcnt drain: orders LDS only. All cross-thread data in
// this kernel flows through LDS; no thread reads another's global stores.
__device__ __forceinline__ void bar_nodrain() {
    asm volatile("s_waitcnt lgkmcnt(0)" ::: "memory");
    __builtin_amdgcn_s_barrier();
    asm volatile("" ::: "memory");
}

__global__ __launch_bounds__(BT, 8)
void sagpool_fused12(const float* __restrict__ x,
                     const int*   __restrict__ ei,
                     const float* __restrict__ theta,
                     float* __restrict__ out,
                     int E_total, int out_x_elems)
{
    __shared__ Smem sm;
    const int g    = blockIdx.x;
    const int tid  = threadIdx.x;
    const int wave = tid >> 6;
    const int lane = tid & 63;
    const int base = g * NPG;
    const bool hasE = tid < NE4;
    const bool hasR = tid < NREM;
    int* sh_edge = (int*)sm.edge4;

    const float4 th = ((const float4*)theta)[lane & 31];

    // ---- x loads FIRST (dot is the critical path), then edges
    float4 v[NCH];
    float4 vR = {0.f, 0.f, 0.f, 0.f};
    const float4* xb4 = (const float4*)(x + (size_t)base * FDIM);
    #pragma unroll
    for (int i = 0; i < NCH; ++i) v[i] = xb4[i * BT + tid];
    if (hasR) vR = xb4[NCH * BT + tid];

    int4 es = {0,0,0,0}, ed = {0,0,0,0};
    if (hasE) {
        es = ((const int4*)(ei + (size_t)g * EPG))[tid];
        ed = ((const int4*)(ei + (size_t)E_total + (size_t)g * EPG))[tid];
    }

    // ---- init: cnt per-wave (same-wave ordering); zp pair slices
    {
        int* cw = sm.cnt[wave];
        for (int i = lane; i < NPG; i += 64) cw[i] = 0;
        double* zw = sm.zp[wave >> 1];
        for (int i = lane; i < NPG; i += 64) zw[i] = 0.0;
    }

    // ---- dot: f64 partial, 3 shfl folds (8 lanes -> 1), 4 partials/node
    #pragma unroll
    for (int i = 0; i < NCH; ++i) {
        int idx = i * BT + tid;
        double dp = (double)v[i].x * th.x + (double)v[i].y * th.y
                  + (double)v[i].z * th.z + (double)v[i].w * th.w;
        dp += __shfl_xor(dp, 1, 64);
        dp += __shfl_xor(dp, 2, 64);
        dp += __shfl_xor(dp, 4, 64);
        if ((lane & 7) == 0)
            sm.part[(idx >> 5) * P4 + ((lane & 31) >> 3)] = dp;
    }
    if (hasR) {
        int idx = NCH * BT + tid;
        double dp = (double)vR.x * th.x + (double)vR.y * th.y
                  + (double)vR.z * th.z + (double)vR.w * th.w;
        dp += __shfl_xor(dp, 1, 64);
        dp += __shfl_xor(dp, 2, 64);
        dp += __shfl_xor(dp, 4, 64);
        if ((lane & 7) == 0)
            sm.part[(idx >> 5) * P4 + ((lane & 31) >> 3)] = dp;
    }

    // ---- edge pack + per-wave degree histogram
    int4 p = {0,0,0,0};
    if (hasE) {
        int4 s4 = es, d4 = ed;
        s4.x -= base; s4.y -= base; s4.z -= base; s4.w -= base;
        d4.x -= base; d4.y -= base; d4.z -= base; d4.w -= base;
        p.x = s4.x | (d4.x << 16); p.y = s4.y | (d4.y << 16);
        p.z = s4.z | (d4.z << 16); p.w = s4.w | (d4.w << 16);
        sm.edge4[tid] = p;
        int* cw = sm.cnt[wave];
        atomicAdd(&cw[s4.x], 1); atomicAdd(&cw[s4.y], 1);
        atomicAdd(&cw[s4.z], 1); atomicAdd(&cw[s4.w], 1);
    }
    bar_nodrain();                                // B2: part, edges, cnt

    // ---- reduce: 1 thread/node: 4 partials + deg -> dis, a
    if (tid < NPG) {
        const double* pr = sm.part + tid * P4;
        double s = (pr[0] + pr[1]) + (pr[2] + pr[3]);
        int deg = 1 + sm.cnt[0][tid] + sm.cnt[1][tid] + sm.cnt[2][tid]
                    + sm.cnt[3][tid] + sm.cnt[4][tid] + sm.cnt[5][tid]
                    + sm.cnt[6][tid] + sm.cnt[7][tid];
        double dis = 1.0 / sqrt((double)deg);
        sm.dis[tid] = dis;
        sm.a[tid]   = s * dis;
    }
    bar_nodrain();                                // B3: dis/a ready

    // ---- z scatter into wave-pair slices (dis[d] hoisted out)
    {
        double* zw = sm.zp[wave >> 1];
        for (int j = tid; j < EPG; j += BT) {
            int e = sh_edge[j];
            atomicAdd(&zw[e >> 16], sm.a[e & 0xffff]);
        }
    }
    bar_nodrain();                                // B4: scatter done

    if (tid < NPG) {
        double zi = sm.a[tid]                     // self-loop term
                  + (sm.zp[0][tid] + sm.zp[1][tid])
                  + (sm.zp[2][tid] + sm.zp[3][tid]);
        sm.z[tid] = zi * sm.dis[tid];
        sm.newid[tid] = -1;
    }
    bar_nodrain();                                // B5: z ready

    // ---- top-k rank, 4 threads/node (25 scans each) + shfl combine
    const bool rk = tid < 4 * NPG;
    const int  n2 = tid >> 2;
    int r = 0;
    double zn = 0.0;
    if (rk) {
        zn = sm.z[n2];
        const int j0 = (tid & 3) * 25;
        #pragma unroll 5
        for (int j = j0; j < j0 + 25; ++j) {
            double zj = sm.z[j];
            r += (int)((zj > zn) | ((zj == zn) & (j < n2)));
        }
    }
    r += __shfl_xor(r, 1, 64);
    r += __shfl_xor(r, 2, 64);                    // all 4 lanes hold full rank
    const bool lead = rk && ((tid & 3) == 0) && (r < KNUM);
    unsigned long long m = __ballot(lead);        // leader bits at lanes 4k
    if (lane == 0) sm.mask7[wave] = m;
    bar_nodrain();                                // B6a: masks ready

    int myrow = -1;
    if (lead) {
        int before = __popcll(m & ((1ull << lane) - 1ull));
        for (int w2 = 0; w2 < wave; ++w2) before += __popcll(sm.mask7[w2]);
        myrow = g * KNUM + before;
        sm.newid[n2]  = myrow;
        sm.scalen[n2] = 1.0f / (1.0f + __expf(-(float)zn));
    }
    bar_nodrain();                                // B6: newid/scalen ready

    // ---- x_new first (big coalesced stream), from the register tile
    float4* outx = (float4*)out;
    #pragma unroll
    for (int i = 0; i < NCH; ++i) {
        int idx = i * BT + tid;
        int row = idx >> 5;
        int nid = sm.newid[row];
        if (nid >= 0) {
            float sc = sm.scalen[row];
            float4 o;
            o.x = v[i].x * sc; o.y = v[i].y * sc;
            o.z = v[i].z * sc; o.w = v[i].w * sc;
            outx[(size_t)nid * 32 + (idx & 31)] = o;
        }
    }
    if (hasR) {
        int idx = NCH * BT + tid;
        int row = idx >> 5;
        int nid = sm.newid[row];
        if (nid >= 0) {
            float sc = sm.scalen[row];
            float4 o;
            o.x = vR.x * sc; o.y = vR.y * sc;
            o.z = vR.z * sc; o.w = vR.w * sc;
            outx[(size_t)nid * 32 + (idx & 31)] = o;
        }
    }

    // ---- edge relabel from register-resident packed edges
    if (hasE) {
        float* e0 = out + out_x_elems;
        float* e1 = e0 + E_total;
        float4 o0, o1;
        {
            int a_ = sm.newid[p.x & 0xffff], b_ = sm.newid[p.x >> 16];
            bool vv = (a_ >= 0) && (b_ >= 0);
            o0.x = vv ? (float)a_ : -1.0f; o1.x = vv ? (float)b_ : -1.0f;
        }
        {
            int a_ = sm.newid[p.y & 0xffff], b_ = sm.newid[p.y >> 16];
            bool vv = (a_ >= 0) && (b_ >= 0);
            o0.y = vv ? (float)a_ : -1.0f; o1.y = vv ? (float)b_ : -1.0f;
        }
        {
            int a_ = sm.newid[p.z & 0xffff], b_ = sm.newid[p.z >> 16];
            bool vv = (a_ >= 0) && (b_ >= 0);
            o0.z = vv ? (float)a_ : -1.0f; o1.z = vv ? (float)b_ : -1.0f;
        }
        {
            int a_ = sm.newid[p.w & 0xffff], b_ = sm.newid[p.w >> 16];
            bool vv = (a_ >= 0) && (b_ >= 0);
            o0.w = vv ? (float)a_ : -1.0f; o1.w = vv ? (float)b_ : -1.0f;
        }
        ((float4*)e0)[(size_t)g * NE4 + tid] = o0;
        ((float4*)e1)[(size_t)g * NE4 + tid] = o1;
    }

    // ---- batch_new last (tiny scattered dwords)
    if (myrow >= 0)
        out[(size_t)out_x_elems + 2 * (size_t)E_total + myrow] = (float)g;
}

extern "C" void kernel_launch(void* const* d_in, const int* in_sizes, int n_in,
                              void* d_out, int out_size, void* d_ws, size_t ws_size,
                              hipStream_t stream)
{
    const float* x     = (const float*)d_in[0];
    const int*   ei    = (const int*)d_in[1];
    const float* theta = (const float*)d_in[3];
    float* out = (float*)d_out;

    const int N = in_sizes[0] / FDIM;        // 100000
    const int E = in_sizes[1] / 2;           // 1600000
    const int B = N / NPG;                   // 1000
    const int out_x_elems = B * KNUM * FDIM; // 10,240,000

    sagpool_fused12<<<dim3(B), dim3(BT), 0, stream>>>(x, ei, theta, out,
                                                      E, out_x_elems);
}